// Round 6
// baseline (450.760 us; speedup 1.0000x reference)
//
#include <hip/hip_runtime.h>
#include <stdint.h>

#define T_TOK 4096
#define DIM   2048
#define INTER 1024
#define NE    9        // 8 routed + 1 shared (as expert 8)
#define NPAIR 12288    // T_TOK * 3 slots

typedef float v4f __attribute__((ext_vector_type(4)));
typedef short v8s __attribute__((ext_vector_type(8)));   // 8 bf16 in 4 VGPRs

__device__ __forceinline__ unsigned short f2bf(float f) {
    unsigned u = __float_as_uint(f);
    u += 0x7fffu + ((u >> 16) & 1u);           // RNE
    return (unsigned short)(u >> 16);
}

__device__ __forceinline__ void gload_lds16(const void* g, void* l) {
    __builtin_amdgcn_global_load_lds(
        (const __attribute__((address_space(1))) void*)g,
        (__attribute__((address_space(3))) void*)l, 16, 0, 0);
}

// ---------------- prep: w1+w3 convert, gate, meta zero — one launch ----------------
__global__ __launch_bounds__(256) void prep_kernel(
        const float* __restrict__ w1,  const float* __restrict__ ws1, unsigned short* __restrict__ w1b,
        const float* __restrict__ w3,  const float* __restrict__ ws3, unsigned short* __restrict__ w3b,
        const float* __restrict__ x,   const float* __restrict__ gw,
        float* __restrict__ wt,        int* __restrict__ ei,
        unsigned short* __restrict__ xb,
        int* __restrict__ meta) {
    if (blockIdx.y < 2) {
        if (blockIdx.x == 0 && blockIdx.y == 0 && threadIdx.x < 18) meta[threadIdx.x] = 0;
        int which = blockIdx.y;
        const float* wmain = (which == 0) ? w1  : w3;
        const float* wsh   = (which == 0) ? ws1 : ws3;
        unsigned short* dst = (which == 0) ? w1b : w3b;
        long long i = (long long)blockIdx.x * 256 + threadIdx.x; // vec4 index
        long long base = i * 4;
        int e = (int)(base >> 21);
        long long within = base & ((1ll << 21) - 1);
        const float* src = (e < 8) ? (wmain + ((long long)e << 21) + within) : (wsh + within);
        float4 f = *(const float4*)src;
        ushort4 u;
        u.x = f2bf(f.x); u.y = f2bf(f.y); u.z = f2bf(f.z); u.w = f2bf(f.w);
        *(ushort4*)(dst + base) = u;
        return;
    }
    // ---- gate path ----
    int t = blockIdx.x;
    if (t >= T_TOK) return;
    __shared__ float xs[DIM];
    __shared__ float lg[8];
    const float* xrow = x + (size_t)t * DIM;
    for (int i = threadIdx.x; i < DIM / 4; i += 256)
        ((float4*)xs)[i] = ((const float4*)xrow)[i];
    __syncthreads();
    for (int i = threadIdx.x; i < DIM / 4; i += 256) {
        float4 f = ((const float4*)xs)[i];
        ushort4 u;
        u.x = f2bf(f.x); u.y = f2bf(f.y); u.z = f2bf(f.z); u.w = f2bf(f.w);
        ((ushort4*)(xb + (size_t)t * DIM))[i] = u;
    }
    int e = threadIdx.x >> 5;
    int l = threadIdx.x & 31;
    const float* g = gw + (size_t)e * DIM;
    float p = 0.f;
    #pragma unroll 8
    for (int d = l; d < DIM; d += 32) p += xs[d] * g[d];
    for (int m = 16; m >= 1; m >>= 1) p += __shfl_xor(p, m, 32);
    if (l == 0) lg[e] = p;
    __syncthreads();
    if (threadIdx.x == 0) {
        float mx = lg[0];
        for (int i = 1; i < 8; i++) mx = fmaxf(mx, lg[i]);
        float pr[8], s = 0.f;
        for (int i = 0; i < 8; i++) { pr[i] = __expf(lg[i] - mx); s += pr[i]; }
        float inv = 1.f / s;
        float b1 = -1.f, b2 = -1.f; int i1 = 0, i2 = 0;
        for (int i = 0; i < 8; i++) {
            float v = pr[i] * inv;
            if (v > b1)      { b2 = b1; i2 = i1; b1 = v; i1 = i; }
            else if (v > b2) { b2 = v;  i2 = i; }
        }
        wt[t * 3 + 0] = b1; wt[t * 3 + 1] = b2; wt[t * 3 + 2] = 1.f;
        ei[t * 3 + 0] = i1; ei[t * 3 + 1] = i2; ei[t * 3 + 2] = 8;
    }
}

// meta layout: [0..9) counts, [9..18) cursors
__global__ __launch_bounds__(256) void count_kernel(const int* __restrict__ ei,
                                                    int* __restrict__ meta) {
    __shared__ int lcnt[NE];
    if (threadIdx.x < NE) lcnt[threadIdx.x] = 0;
    __syncthreads();
    int t = blockIdx.x * 256 + threadIdx.x;
    #pragma unroll
    for (int s = 0; s < 3; s++) atomicAdd(&lcnt[ei[t * 3 + s]], 1);
    __syncthreads();
    if (threadIdx.x < NE) atomicAdd(&meta[threadIdx.x], lcnt[threadIdx.x]);
}

// block-aggregated placement; computes expert offsets locally
__global__ __launch_bounds__(256) void fill_kernel(const int* __restrict__ ei,
                                                   const float* __restrict__ wt,
                                                   int* __restrict__ meta,
                                                   int* __restrict__ pair_tok,
                                                   float* __restrict__ pair_w,
                                                   int* __restrict__ slots) {
    __shared__ int lcnt[NE], lbase[NE], loffs[NE];
    if (threadIdx.x < NE) lcnt[threadIdx.x] = 0;
    __syncthreads();
    int t = blockIdx.x * 256 + threadIdx.x;
    int es[3], lp[3];
    #pragma unroll
    for (int s = 0; s < 3; s++) {
        es[s] = ei[t * 3 + s];
        lp[s] = atomicAdd(&lcnt[es[s]], 1);
    }
    __syncthreads();
    if (threadIdx.x < NE)
        lbase[threadIdx.x] = atomicAdd(&meta[9 + threadIdx.x], lcnt[threadIdx.x]);
    if (threadIdx.x == 0) {
        int a = 0;
        #pragma unroll
        for (int e = 0; e < NE; e++) { loffs[e] = a; a += meta[e]; }
    }
    __syncthreads();
    #pragma unroll
    for (int s = 0; s < 3; s++) {
        int g = loffs[es[s]] + lbase[es[s]] + lp[s];
        pair_tok[g] = t;
        pair_w[g] = wt[t * 3 + s];
        slots[t * 3 + s] = g;
    }
}

// ---------------- GEMM1: G[p,i] = silu(x.w1^T) * (x.w3^T) * route_w, bf16 out ----------------
// BM=128, BN=64, BK=64, 256 threads (4 waves, 2x2), dual accumulator (w1,w3)
// Grid mapping: IDENTITY (R2/R5-measured-best; R3/R4 swizzles both regressed).
// y in [32,40): fused w2 fp32->bf16 conversion (113MB HBM riding the compute launch).
// OCCUPANCY: 64 arch VGPR + 64 acc = 128/wave -> launch_bounds(256,3).
__global__ __launch_bounds__(256, 3) void gemm1_kernel(
        const unsigned short* __restrict__ xb,
        const unsigned short* __restrict__ w1b,
        const unsigned short* __restrict__ w3b,
        unsigned short* __restrict__ G,
        const int* __restrict__ meta,
        const int* __restrict__ pair_tok,
        const float* __restrict__ pair_w,
        const float* __restrict__ w2f,
        const float* __restrict__ ws2,
        unsigned short* __restrict__ w2b) {
    int e  = blockIdx.z;
    int by = blockIdx.y;
    int bx = blockIdx.x;

    if (by >= 32) {
        // ---- fused w2 conversion path: 1152 blocks x 16 float4/thread ----
        int flat = (e * 8 + (by - 32)) * 16 + bx;  // [0,1152)
        long long vbase = (long long)flat * 4096 + threadIdx.x;
        #pragma unroll
        for (int it = 0; it < 16; ++it) {
            long long i = vbase + it * 256;
            long long base = i * 4;
            int ew = (int)(base >> 21);
            long long within = base & ((1ll << 21) - 1);
            const float* src = (ew < 8) ? (w2f + ((long long)ew << 21) + within) : (ws2 + within);
            float4 f = *(const float4*)src;
            ushort4 u;
            u.x = f2bf(f.x); u.y = f2bf(f.y); u.z = f2bf(f.z); u.w = f2bf(f.w);
            *(ushort4*)(w2b + base) = u;
        }
        return;
    }
    int cnt = meta[e];
    int m0 = by * 128;
    if (m0 >= cnt) return;
    int off = 0;
    for (int i = 0; i < e; i++) off += meta[i];   // uniform scalar scan
    int n0 = bx * 64;

    __shared__ __align__(16) unsigned short As[128 * 64];
    __shared__ __align__(16) unsigned short B1s[64 * 64];
    __shared__ __align__(16) unsigned short B3s[64 * 64];

    int tid = threadIdx.x;
    int wave = tid >> 6, lane = tid & 63;
    int kc = (lane & 7) ^ (lane >> 3);          // XOR phase: j-invariant

    const unsigned short* sbase;
    unsigned short* ldst;
    unsigned soff[8];
    if (wave < 2) {
        sbase = xb;
        ldst = As + wave * 4096;
        #pragma unroll
        for (int j = 0; j < 8; j++) {
            int row = (wave * 8 + j) * 8 + (lane >> 3);
            int p = m0 + row; p = p < cnt ? p : cnt - 1;
            int tok = pair_tok[off + p];
            soff[j] = (unsigned)tok * DIM + (unsigned)(kc * 8);
        }
    } else {
        const unsigned short* wsrc = (wave == 2) ? w1b : w3b;
        ldst = (wave == 2) ? B1s : B3s;
        sbase = wsrc + ((size_t)e * INTER + n0 + (lane >> 3)) * DIM + kc * 8;
    }

    int wm = wave >> 1, wn = wave & 1;
    int mb = wm * 64, nb = wn * 32;
    v4f zero4 = {0.f, 0.f, 0.f, 0.f};
    v4f acc1[4][2], acc3[4][2];
    #pragma unroll
    for (int i = 0; i < 4; i++)
        #pragma unroll
        for (int j = 0; j < 2; j++) { acc1[i][j] = zero4; acc3[i][j] = zero4; }

    for (int k0 = 0; k0 < DIM; k0 += 64) {
        if (wave < 2) {
            #pragma unroll
            for (int j = 0; j < 8; j++)
                gload_lds16(sbase + soff[j] + k0, ldst + j * 512);
        } else {
            #pragma unroll
            for (int j = 0; j < 8; j++)
                gload_lds16(sbase + (unsigned)(j * 8 * DIM) + k0, ldst + j * 512);
        }
        __syncthreads();
        #pragma unroll
        for (int s = 0; s < 2; s++) {
            int kk = s * 4 + (lane >> 4);
            v8s a[4], b1[2], b3[2];
            #pragma unroll
            for (int mt = 0; mt < 4; mt++) {
                int r = mb + mt * 16 + (lane & 15);
                a[mt] = *(const v8s*)&As[r * 64 + ((kk ^ (r & 7)) << 3)];
            }
            #pragma unroll
            for (int nt = 0; nt < 2; nt++) {
                int n = nb + nt * 16 + (lane & 15);
                int o = n * 64 + ((kk ^ (n & 7)) << 3);
                b1[nt] = *(const v8s*)&B1s[o];
                b3[nt] = *(const v8s*)&B3s[o];
            }
            #pragma unroll
            for (int mt = 0; mt < 4; mt++)
                #pragma unroll
                for (int nt = 0; nt < 2; nt++) {
                    acc1[mt][nt] = __builtin_amdgcn_mfma_f32_16x16x32_bf16(a[mt], b1[nt], acc1[mt][nt], 0, 0, 0);
                    acc3[mt][nt] = __builtin_amdgcn_mfma_f32_16x16x32_bf16(a[mt], b3[nt], acc3[mt][nt], 0, 0, 0);
                }
        }
        __syncthreads();
    }

    #pragma unroll
    for (int mt = 0; mt < 4; mt++) {
        #pragma unroll
        for (int r = 0; r < 4; r++) {
            int row = mb + mt * 16 + ((lane >> 4) << 2) + r;
            int p = m0 + row;
            if (p < cnt) {
                float w = pair_w[off + p];
                size_t gbase = (size_t)(off + p) * INTER + n0 + nb;
                #pragma unroll
                for (int nt = 0; nt < 2; nt++) {
                    float h1 = acc1[mt][nt][r];
                    float h3 = acc3[mt][nt][r];
                    float gv = h1 / (1.f + __expf(-h1)) * h3 * w;
                    G[gbase + nt * 16 + (lane & 15)] = f2bf(gv);
                }
            }
        }
    }
}

// ---------------- GEMM2: eo[p,d] = G[p,:] . w2[e][d,:] — 8-PHASE 256x256 TEMPLATE ----------
// BM=BN=256, BK=64, 512 threads (8 waves, 2M x 4N), double-buffered LDS (128 KiB).
// Plain-HIP port of the 8-phase counted-vmcnt schedule (T3+T4+T5):
//  - each iteration processes 2 K-tiles (T0=2i in buf0 phases 0-3, T1=2i+1 in buf1 phases 4-7)
//  - per phase: {ds_read subtile, 1 half-tile global_load_lds stage, s_barrier,
//                lgkmcnt(0)+sched_barrier, setprio(1), 16 MFMA, setprio(0), s_barrier}
//  - stage slots chosen so a region is re-staged only AFTER its last consuming phase:
//      ph0: T1.B0   ph1: T1.B1   ph2: T2.A0  ph3: T2.A1
//      ph4: T2.B0   ph5: T2.B1   ph6: T3.A0  ph7: T3.A1      (T2,T3 guarded by i<7)
//  - vmcnt(4) before the end-barrier of phases 3 and 7: allows the 2 newest half-tiles
//    (4 loads) to stay in flight across the barrier; FIFO completion (m135) guarantees
//    the tiles needed next are landed. Never vmcnt(0) in the loop.
// LDS layout: per tile [256 rows][64 k] bf16, 8-elem chunk XOR swizzle
// (chunk ^= row&7) — same conflict-free scheme as gemm1 (measured 0 conflicts);
// linear LDS dest + pre-swizzled global source (m173 pattern, gload_lds-compatible).
__global__ __launch_bounds__(512, 2) void gemm2_kernel(
        const unsigned short* __restrict__ G,
        const unsigned short* __restrict__ w2b,
        unsigned short* __restrict__ eo,
        const int* __restrict__ meta) {
    int e = blockIdx.z;
    int cnt = meta[e];
    int m0 = blockIdx.y * 256;
    if (m0 >= cnt) return;
    int off = 0;
    for (int i = 0; i < e; i++) off += meta[i];
    int n0 = blockIdx.x * 256;

    __shared__ __align__(16) unsigned short As[2][256 * 64];
    __shared__ __align__(16) unsigned short Bs[2][256 * 64];

    int tid = threadIdx.x;
    int wave = tid >> 6, lane = tid & 63;
    int wm = wave >> 2, wn = wave & 3;
    int l15 = lane & 15;
    int kS0 = (lane >> 4);        // k-chunk for s=0 MFMA step
    int kS1 = 4 + (lane >> 4);    // k-chunk for s=1

    // staging: half-tile = 128 rows x 64 k = 1024 chunks of 16B; thread covers c0 and c1
    int c0 = tid, c1 = tid + 512;
    int r0 = c0 >> 3, r1 = c1 >> 3;
    unsigned kc0 = (unsigned)(((c0 & 7) ^ (r0 & 7)) * 8);
    unsigned kc1 = (unsigned)(((c1 & 7) ^ (r1 & 7)) * 8);
    const unsigned short* Agb = G + (size_t)(off + m0) * INTER;
    const unsigned short* Bgb = w2b + ((size_t)e * DIM + n0) * INTER;

#define G2_STAGE_A(buf, half, k0) do { \
    gload_lds16(Agb + (size_t)((half) * 128 + r0) * INTER + (k0) + kc0, &As[buf][(half) * 8192 + c0 * 8]); \
    gload_lds16(Agb + (size_t)((half) * 128 + r1) * INTER + (k0) + kc1, &As[buf][(half) * 8192 + c1 * 8]); \
} while (0)
#define G2_STAGE_B(buf, half, k0) do { \
    gload_lds16(Bgb + (size_t)((half) * 128 + r0) * INTER + (k0) + kc0, &Bs[buf][(half) * 8192 + c0 * 8]); \
    gload_lds16(Bgb + (size_t)((half) * 128 + r1) * INTER + (k0) + kc1, &Bs[buf][(half) * 8192 + c1 * 8]); \
} while (0)
#define G2_SBAR()  asm volatile("s_barrier" ::: "memory")
#define G2_LGKM0() do { asm volatile("s_waitcnt lgkmcnt(0)" ::: "memory"); \
                        __builtin_amdgcn_sched_barrier(0); } while (0)
#define G2_VMC4()  asm volatile("s_waitcnt vmcnt(4)" ::: "memory")
#define G2_LDF(tile, row, kch) (*(const v8s*)&(tile)[(row) * 64 + (((kch) ^ ((row) & 7)) << 3)])
#define G2_MFMA16(av, b_lo, b_hi, nlo, nhi) do { \
    __builtin_amdgcn_s_setprio(1); \
    _Pragma("unroll") \
    for (int mf = 0; mf < 8; mf++) { \
        acc[mf][nlo] = __builtin_amdgcn_mfma_f32_16x16x32_bf16(av[mf], b_lo, acc[mf][nlo], 0, 0, 0); \
        acc[mf][nhi] = __builtin_amdgcn_mfma_f32_16x16x32_bf16(av[mf], b_hi, acc[mf][nhi], 0, 0, 0); \
    } \
    __builtin_amdgcn_s_setprio(0); \
} while (0)

    v4f acc[8][4];
    v4f zero4 = {0.f, 0.f, 0.f, 0.f};
    #pragma unroll
    for (int i = 0; i < 8; i++)
        #pragma unroll
        for (int j = 0; j < 4; j++) acc[i][j] = zero4;

    // prologue: tile0 (A+B) -> buf0; tile1 (A only) -> buf1; wait tile0 landed (allow 4)
    G2_STAGE_A(0, 0, 0); G2_STAGE_A(0, 1, 0); G2_STAGE_B(0, 0, 0); G2_STAGE_B(0, 1, 0);
    G2_STAGE_A(1, 0, 64); G2_STAGE_A(1, 1, 64);
    G2_VMC4();
    G2_SBAR();

    for (int it = 0; it < 8; ++it) {
        int k1 = (2 * it + 1) * 64;
        int k2 = (2 * it + 2) * 64;
        int k3 = (2 * it + 3) * 64;
        bool more = (it < 7);
        v8s a0[8], a1[8], bl, bh;

        // ---- phase 0: T0 reads A.s0 + B.s0.nf{0,1}; stage T1.B0 ----
        #pragma unroll
        for (int mf = 0; mf < 8; mf++) a0[mf] = G2_LDF(As[0], wm * 128 + mf * 16 + l15, kS0);
        bl = G2_LDF(Bs[0], wn * 64 + 0 * 16 + l15, kS0);
        bh = G2_LDF(Bs[0], wn * 64 + 1 * 16 + l15, kS0);
        G2_STAGE_B(1, 0, k1);
        G2_SBAR(); G2_LGKM0();
        G2_MFMA16(a0, bl, bh, 0, 1);
        G2_SBAR();

        // ---- phase 1: T0 reads A.s1 + B.s0.nf{2,3}; stage T1.B1 ----
        #pragma unroll
        for (int mf = 0; mf < 8; mf++) a1[mf] = G2_LDF(As[0], wm * 128 + mf * 16 + l15, kS1);
        bl = G2_LDF(Bs[0], wn * 64 + 2 * 16 + l15, kS0);
        bh = G2_LDF(Bs[0], wn * 64 + 3 * 16 + l15, kS0);
        G2_STAGE_B(1, 1, k1);
        G2_SBAR(); G2_LGKM0();
        G2_MFMA16(a0, bl, bh, 2, 3);
        G2_SBAR();

        // ---- phase 2: T0 reads B.s1.nf{0,1}; stage T2.A0 (buf0.A free after ph1) ----
        bl = G2_LDF(Bs[0], wn * 64 + 0 * 16 + l15, kS1);
        bh = G2_LDF(Bs[0], wn * 64 + 1 * 16 + l15, kS1);
        if (more) G2_STAGE_A(0, 0, k2);
        G2_SBAR(); G2_LGKM0();
        G2_MFMA16(a1, bl, bh, 0, 1);
        G2_SBAR();

        // ---- phase 3: T0 reads B.s1.nf{2,3}; stage T2.A1; vmcnt(4) gate for T1.B ----
        bl = G2_LDF(Bs[0], wn * 64 + 2 * 16 + l15, kS1);
        bh = G2_LDF(Bs[0], wn * 64 + 3 * 16 + l15, kS1);
        if (more) G2_STAGE_A(0, 1, k2);
        G2_SBAR(); G2_LGKM0();
        G2_MFMA16(a1, bl, bh, 2, 3);
        G2_VMC4();
        G2_SBAR();

        // ---- phase 4: T1 reads A.s0 + B.s0.nf{0,1}; stage T2.B0 (buf0.B free after ph3) ----
        #pragma unroll
        for (int mf = 0; mf < 8; mf++) a0[mf] = G2_LDF(As[1], wm * 128 + mf * 16 + l15, kS0);
        bl = G2_LDF(Bs[1], wn * 64 + 0 * 16 + l15, kS0);
        bh = G2_LDF(Bs[1], wn * 64 + 1 * 16 + l15, kS0);
        if (more) G2_STAGE_B(0, 0, k2);
        G2_SBAR(); G2_LGKM0();
        G2_MFMA16(a0, bl, bh, 0, 1);
        G2_SBAR();

        // ---- phase 5: T1 reads A.s1 + B.s0.nf{2,3}; stage T2.B1 ----
        #pragma unroll
        for (int mf = 0; mf < 8; mf++) a1[mf] = G2_LDF(As[1], wm * 128 + mf * 16 + l15, kS1);
        bl = G2_LDF(Bs[1], wn * 64 + 2 * 16 + l15, kS0);
        bh = G2_LDF(Bs[1], wn * 64 + 3 * 16 + l15, kS0);
        if (more) G2_STAGE_B(0, 1, k2);
        G2_SBAR(); G2_LGKM0();
        G2_MFMA16(a0, bl, bh, 2, 3);
        G2_SBAR();

        // ---- phase 6: T1 reads B.s1.nf{0,1}; stage T3.A0 (buf1.A free after ph5) ----
        bl = G2_LDF(Bs[1], wn * 64 + 0 * 16 + l15, kS1);
        bh = G2_LDF(Bs[1], wn * 64 + 1 * 16 + l15, kS1);
        if (more) G2_STAGE_A(1, 0, k3);
        G2_SBAR(); G2_LGKM0();
        G2_MFMA16(a1, bl, bh, 0, 1);
        G2_SBAR();

        // ---- phase 7: T1 reads B.s1.nf{2,3}; stage T3.A1; vmcnt(4) gate for T2 ----
        bl = G2_LDF(Bs[1], wn * 64 + 2 * 16 + l15, kS1);
        bh = G2_LDF(Bs[1], wn * 64 + 3 * 16 + l15, kS1);
        if (more) G2_STAGE_A(1, 1, k3);
        G2_SBAR(); G2_LGKM0();
        G2_MFMA16(a1, bl, bh, 2, 3);
        G2_VMC4();
        G2_SBAR();
    }

    // epilogue: register-only -> bf16 stores
    #pragma unroll
    for (int mf = 0; mf < 8; mf++) {
        #pragma unroll
        for (int r = 0; r < 4; r++) {
            int row = wm * 128 + mf * 16 + ((lane >> 4) << 2) + r;
            int p = m0 + row;
            if (p < cnt) {
                unsigned short* ob = eo + (size_t)(off + p) * DIM + n0 + wn * 64;
                #pragma unroll
                for (int nf = 0; nf < 4; nf++)
                    ob[nf * 16 + l15] = f2bf(acc[mf][nf][r]);
            }
        }
    }
#undef G2_STAGE_A
#undef G2_STAGE_B
#undef G2_SBAR
#undef G2_LGKM0
#undef G2_VMC4
#undef G2_LDF
#undef G2_MFMA16
}

// ---------------- combine: out[t,:] = eo[p1,:] + eo[p2,:] + eo[p3,:] ----------------
__global__ __launch_bounds__(256) void combine_kernel(const unsigned short* __restrict__ eo,
                                                      const int* __restrict__ slots,
                                                      float* __restrict__ out) {
    int t = blockIdx.x;
    int p0 = slots[t * 3 + 0], p1 = slots[t * 3 + 1], p2 = slots[t * 3 + 2];
    const ushort4* r0 = (const ushort4*)(eo + (size_t)p0 * DIM);
    const ushort4* r1 = (const ushort4*)(eo + (size_t)p1 * DIM);
    const ushort4* r2 = (const ushort4*)(eo + (size_t)p2 * DIM);
    float4* o = (float4*)(out + (size_t)t * DIM);
    for (int i = threadIdx.x; i < DIM / 4; i += 256) {
        ushort4 a = r0[i], b = r1[i], c = r2[i];
        float4 v;
        v.x = __uint_as_float((unsigned)a.x << 16) + __uint_as_float((unsigned)b.x << 16) + __uint_as_float((unsigned)c.x << 16);
        v.y = __uint_as_float((unsigned)a.y << 16) + __uint_as_float((unsigned)b.y << 16) + __uint_as_float((unsigned)c.y << 16);
        v.z = __uint_as_float((unsigned)a.z << 16) + __uint_as_float((unsigned)b.z << 16) + __uint_as_float((unsigned)c.z << 16);
        v.w = __uint_as_float((unsigned)a.w << 16) + __uint_as_float((unsigned)b.w << 16) + __uint_as_float((unsigned)c.w << 16);
        o[i] = v;
    }
}

// ---------------- launch ----------------
extern "C" void kernel_launch(void* const* d_in, const int* in_sizes, int n_in,
                              void* d_out, int out_size, void* d_ws, size_t ws_size,
                              hipStream_t stream) {
    const float* x   = (const float*)d_in[0];
    const float* gw  = (const float*)d_in[1];
    const float* w1  = (const float*)d_in[2];
    const float* w2  = (const float*)d_in[3];
    const float* w3  = (const float*)d_in[4];
    const float* ws1 = (const float*)d_in[5];
    const float* ws2 = (const float*)d_in[6];
    const float* ws3 = (const float*)d_in[7];
    float* out = (float*)d_out;

    char* p = (char*)d_ws;
    auto alloc = [&](size_t bytes) {
        void* r = (void*)p;
        p += (bytes + 255) & ~(size_t)255;
        return r;
    };
    unsigned short* xb  = (unsigned short*)alloc((size_t)T_TOK * DIM * 2);
    unsigned short* w1b = (unsigned short*)alloc((size_t)NE * INTER * DIM * 2);
    unsigned short* w3b = (unsigned short*)alloc((size_t)NE * INTER * DIM * 2);
    unsigned short* w2b = (unsigned short*)alloc((size_t)NE * DIM * INTER * 2);
    unsigned short* G   = (unsigned short*)alloc((size_t)NPAIR * INTER * 2);
    int*   ei    = (int*)alloc((size_t)T_TOK * 3 * 4);
    float* wt    = (float*)alloc((size_t)T_TOK * 3 * 4);
    int*   ptok  = (int*)alloc((size_t)NPAIR * 4);
    float* pw    = (float*)alloc((size_t)NPAIR * 4);
    int*   slots = (int*)alloc((size_t)NPAIR * 4);
    int*   meta  = (int*)alloc(32 * 4);
    // eo (12288 x 2048 bf16 = 50.3 MB) aliases w1b+w3b (75.5 MB): dead after gemm1
    unsigned short* eo = w1b;

    int wgrid = (NE * INTER * DIM / 4) / 256;   // 18432 per matrix
    prep_kernel<<<dim3(wgrid, 3), 256, 0, stream>>>(w1, ws1, w1b, w3, ws3, w3b,
                                                    x, gw, wt, ei, xb, meta);
    count_kernel<<<T_TOK / 256, 256, 0, stream>>>(ei, meta);
    fill_kernel<<<T_TOK / 256, 256, 0, stream>>>(ei, wt, meta, ptok, pw, slots);
    gemm1_kernel<<<dim3(INTER / 64, 40, NE), 256, 0, stream>>>(xb, w1b, w3b, G, meta, ptok, pw,
                                                               w2, ws2, w2b);
    gemm2_kernel<<<dim3(DIM / 256, 16, NE), 512, 0, stream>>>(G, w2b, eo, meta);
    combine_kernel<<<T_TOK, 256, 0, stream>>>(eo, slots, out);
}

// Round 7
// 438.748 us; speedup vs baseline: 1.0274x; 1.0274x over previous
//
#include <hip/hip_runtime.h>
#include <stdint.h>

#define T_TOK 4096
#define DIM   2048
#define INTER 1024
#define NE    9        // 8 routed + 1 shared (as expert 8)
#define NPAIR 12288    // T_TOK * 3 slots
#define WCVT  ((NE * INTER * DIM / 4) / 256)   // 18432 cvt blocks per matrix

typedef float v4f __attribute__((ext_vector_type(4)));
typedef short v8s __attribute__((ext_vector_type(8)));   // 8 bf16 in 4 VGPRs

__device__ __forceinline__ unsigned short f2bf(float f) {
    unsigned u = __float_as_uint(f);
    u += 0x7fffu + ((u >> 16) & 1u);           // RNE
    return (unsigned short)(u >> 16);
}

__device__ __forceinline__ void gload_lds16(const void* g, void* l) {
    __builtin_amdgcn_global_load_lds(
        (const __attribute__((address_space(1))) void*)g,
        (__attribute__((address_space(3))) void*)l, 16, 0, 0);
}

// ---------------- prep: w1+w3 convert, gate, meta zero — one 1D launch ----------------
// Flat grid [0, 2*WCVT + T_TOK): blocks [0,WCVT) = w1 cvt, [WCVT,2*WCVT) = w3 cvt,
// [2*WCVT, +T_TOK) = gate. (R5 used dim3(WCVT,3) — 14336 phantom gate blocks at y==2.)
__global__ __launch_bounds__(256) void prep_kernel(
        const float* __restrict__ w1,  const float* __restrict__ ws1, unsigned short* __restrict__ w1b,
        const float* __restrict__ w3,  const float* __restrict__ ws3, unsigned short* __restrict__ w3b,
        const float* __restrict__ x,   const float* __restrict__ gw,
        float* __restrict__ wt,        int* __restrict__ ei,
        unsigned short* __restrict__ xb,
        int* __restrict__ meta) {
    int b = blockIdx.x;
    if (b < 2 * WCVT) {
        if (b == 0 && threadIdx.x < 18) meta[threadIdx.x] = 0;
        int which = b / WCVT;
        const float* wmain = (which == 0) ? w1  : w3;
        const float* wsh   = (which == 0) ? ws1 : ws3;
        unsigned short* dst = (which == 0) ? w1b : w3b;
        long long i = (long long)(b % WCVT) * 256 + threadIdx.x; // vec4 index
        long long base = i * 4;
        int e = (int)(base >> 21);
        long long within = base & ((1ll << 21) - 1);
        const float* src = (e < 8) ? (wmain + ((long long)e << 21) + within) : (wsh + within);
        float4 f = *(const float4*)src;
        ushort4 u;
        u.x = f2bf(f.x); u.y = f2bf(f.y); u.z = f2bf(f.z); u.w = f2bf(f.w);
        *(ushort4*)(dst + base) = u;
        return;
    }
    // ---- gate path ----
    int t = b - 2 * WCVT;
    __shared__ float xs[DIM];
    __shared__ float lg[8];
    const float* xrow = x + (size_t)t * DIM;
    for (int i = threadIdx.x; i < DIM / 4; i += 256)
        ((float4*)xs)[i] = ((const float4*)xrow)[i];
    __syncthreads();
    for (int i = threadIdx.x; i < DIM / 4; i += 256) {
        float4 f = ((const float4*)xs)[i];
        ushort4 u;
        u.x = f2bf(f.x); u.y = f2bf(f.y); u.z = f2bf(f.z); u.w = f2bf(f.w);
        ((ushort4*)(xb + (size_t)t * DIM))[i] = u;
    }
    int e = threadIdx.x >> 5;
    int l = threadIdx.x & 31;
    const float* g = gw + (size_t)e * DIM;
    float p = 0.f;
    #pragma unroll 8
    for (int d = l; d < DIM; d += 32) p += xs[d] * g[d];
    for (int m = 16; m >= 1; m >>= 1) p += __shfl_xor(p, m, 32);
    if (l == 0) lg[e] = p;
    __syncthreads();
    if (threadIdx.x == 0) {
        float mx = lg[0];
        for (int i = 1; i < 8; i++) mx = fmaxf(mx, lg[i]);
        float pr[8], s = 0.f;
        for (int i = 0; i < 8; i++) { pr[i] = __expf(lg[i] - mx); s += pr[i]; }
        float inv = 1.f / s;
        float b1 = -1.f, b2 = -1.f; int i1 = 0, i2 = 0;
        for (int i = 0; i < 8; i++) {
            float v = pr[i] * inv;
            if (v > b1)      { b2 = b1; i2 = i1; b1 = v; i1 = i; }
            else if (v > b2) { b2 = v;  i2 = i; }
        }
        wt[t * 3 + 0] = b1; wt[t * 3 + 1] = b2; wt[t * 3 + 2] = 1.f;
        ei[t * 3 + 0] = i1; ei[t * 3 + 1] = i2; ei[t * 3 + 2] = 8;
    }
}

// meta layout: [0..9) counts, [9..18) cursors
__global__ __launch_bounds__(256) void count_kernel(const int* __restrict__ ei,
                                                    int* __restrict__ meta) {
    __shared__ int lcnt[NE];
    if (threadIdx.x < NE) lcnt[threadIdx.x] = 0;
    __syncthreads();
    int t = blockIdx.x * 256 + threadIdx.x;
    #pragma unroll
    for (int s = 0; s < 3; s++) atomicAdd(&lcnt[ei[t * 3 + s]], 1);
    __syncthreads();
    if (threadIdx.x < NE) atomicAdd(&meta[threadIdx.x], lcnt[threadIdx.x]);
}

// block-aggregated placement; computes expert offsets locally
__global__ __launch_bounds__(256) void fill_kernel(const int* __restrict__ ei,
                                                   const float* __restrict__ wt,
                                                   int* __restrict__ meta,
                                                   int* __restrict__ pair_tok,
                                                   float* __restrict__ pair_w,
                                                   int* __restrict__ slots) {
    __shared__ int lcnt[NE], lbase[NE], loffs[NE];
    if (threadIdx.x < NE) lcnt[threadIdx.x] = 0;
    __syncthreads();
    int t = blockIdx.x * 256 + threadIdx.x;
    int es[3], lp[3];
    #pragma unroll
    for (int s = 0; s < 3; s++) {
        es[s] = ei[t * 3 + s];
        lp[s] = atomicAdd(&lcnt[es[s]], 1);
    }
    __syncthreads();
    if (threadIdx.x < NE)
        lbase[threadIdx.x] = atomicAdd(&meta[9 + threadIdx.x], lcnt[threadIdx.x]);
    if (threadIdx.x == 0) {
        int a = 0;
        #pragma unroll
        for (int e = 0; e < NE; e++) { loffs[e] = a; a += meta[e]; }
    }
    __syncthreads();
    #pragma unroll
    for (int s = 0; s < 3; s++) {
        int g = loffs[es[s]] + lbase[es[s]] + lp[s];
        pair_tok[g] = t;
        pair_w[g] = wt[t * 3 + s];
        slots[t * 3 + s] = g;
    }
}

// ---------------- GEMM1: G[p,i] = silu(x.w1^T) * (x.w3^T) * route_w, bf16 out ----------------
// BM=128, BN=64, BK=64, 256 threads (4 waves, 2x2), dual accumulator (w1,w3)
// Grid mapping: IDENTITY (R2/R5-measured-best; R3/R4 swizzles both regressed).
// y in [32,40): fused w2 fp32->bf16 conversion (113MB HBM riding the compute launch).
// OCCUPANCY: 64 arch VGPR + 64 acc = 128/wave; HW wall = 16 waves/CU at 128 regs (m69),
// already achieved (4 blocks x 4 waves). Structural escapes measured negative here:
// 8-phase 256^2 (R6, +10us: 1 block/CU + 1.5-round tail), XCD swizzles (R3/R4).
__global__ __launch_bounds__(256, 3) void gemm1_kernel(
        const unsigned short* __restrict__ xb,
        const unsigned short* __restrict__ w1b,
        const unsigned short* __restrict__ w3b,
        unsigned short* __restrict__ G,
        const int* __restrict__ meta,
        const int* __restrict__ pair_tok,
        const float* __restrict__ pair_w,
        const float* __restrict__ w2f,
        const float* __restrict__ ws2,
        unsigned short* __restrict__ w2b) {
    int e  = blockIdx.z;
    int by = blockIdx.y;
    int bx = blockIdx.x;

    if (by >= 32) {
        // ---- fused w2 conversion path: 1152 blocks x 16 float4/thread ----
        int flat = (e * 8 + (by - 32)) * 16 + bx;  // [0,1152)
        long long vbase = (long long)flat * 4096 + threadIdx.x;
        #pragma unroll
        for (int it = 0; it < 16; ++it) {
            long long i = vbase + it * 256;
            long long base = i * 4;
            int ew = (int)(base >> 21);
            long long within = base & ((1ll << 21) - 1);
            const float* src = (ew < 8) ? (w2f + ((long long)ew << 21) + within) : (ws2 + within);
            float4 f = *(const float4*)src;
            ushort4 u;
            u.x = f2bf(f.x); u.y = f2bf(f.y); u.z = f2bf(f.z); u.w = f2bf(f.w);
            *(ushort4*)(w2b + base) = u;
        }
        return;
    }
    int cnt = meta[e];
    int m0 = by * 128;
    if (m0 >= cnt) return;
    int off = 0;
    for (int i = 0; i < e; i++) off += meta[i];   // uniform scalar scan
    int n0 = bx * 64;

    __shared__ __align__(16) unsigned short As[128 * 64];
    __shared__ __align__(16) unsigned short B1s[64 * 64];
    __shared__ __align__(16) unsigned short B3s[64 * 64];

    int tid = threadIdx.x;
    int wave = tid >> 6, lane = tid & 63;
    int kc = (lane & 7) ^ (lane >> 3);          // XOR phase: j-invariant

    const unsigned short* sbase;
    unsigned short* ldst;
    unsigned soff[8];
    if (wave < 2) {
        sbase = xb;
        ldst = As + wave * 4096;
        #pragma unroll
        for (int j = 0; j < 8; j++) {
            int row = (wave * 8 + j) * 8 + (lane >> 3);
            int p = m0 + row; p = p < cnt ? p : cnt - 1;
            int tok = pair_tok[off + p];
            soff[j] = (unsigned)tok * DIM + (unsigned)(kc * 8);
        }
    } else {
        const unsigned short* wsrc = (wave == 2) ? w1b : w3b;
        ldst = (wave == 2) ? B1s : B3s;
        sbase = wsrc + ((size_t)e * INTER + n0 + (lane >> 3)) * DIM + kc * 8;
    }

    int wm = wave >> 1, wn = wave & 1;
    int mb = wm * 64, nb = wn * 32;
    v4f zero4 = {0.f, 0.f, 0.f, 0.f};
    v4f acc1[4][2], acc3[4][2];
    #pragma unroll
    for (int i = 0; i < 4; i++)
        #pragma unroll
        for (int j = 0; j < 2; j++) { acc1[i][j] = zero4; acc3[i][j] = zero4; }

    for (int k0 = 0; k0 < DIM; k0 += 64) {
        if (wave < 2) {
            #pragma unroll
            for (int j = 0; j < 8; j++)
                gload_lds16(sbase + soff[j] + k0, ldst + j * 512);
        } else {
            #pragma unroll
            for (int j = 0; j < 8; j++)
                gload_lds16(sbase + (unsigned)(j * 8 * DIM) + k0, ldst + j * 512);
        }
        __syncthreads();
        #pragma unroll
        for (int s = 0; s < 2; s++) {
            int kk = s * 4 + (lane >> 4);
            v8s a[4], b1[2], b3[2];
            #pragma unroll
            for (int mt = 0; mt < 4; mt++) {
                int r = mb + mt * 16 + (lane & 15);
                a[mt] = *(const v8s*)&As[r * 64 + ((kk ^ (r & 7)) << 3)];
            }
            #pragma unroll
            for (int nt = 0; nt < 2; nt++) {
                int n = nb + nt * 16 + (lane & 15);
                int o = n * 64 + ((kk ^ (n & 7)) << 3);
                b1[nt] = *(const v8s*)&B1s[o];
                b3[nt] = *(const v8s*)&B3s[o];
            }
            #pragma unroll
            for (int mt = 0; mt < 4; mt++)
                #pragma unroll
                for (int nt = 0; nt < 2; nt++) {
                    acc1[mt][nt] = __builtin_amdgcn_mfma_f32_16x16x32_bf16(a[mt], b1[nt], acc1[mt][nt], 0, 0, 0);
                    acc3[mt][nt] = __builtin_amdgcn_mfma_f32_16x16x32_bf16(a[mt], b3[nt], acc3[mt][nt], 0, 0, 0);
                }
        }
        __syncthreads();
    }

    #pragma unroll
    for (int mt = 0; mt < 4; mt++) {
        #pragma unroll
        for (int r = 0; r < 4; r++) {
            int row = mb + mt * 16 + ((lane >> 4) << 2) + r;
            int p = m0 + row;
            if (p < cnt) {
                float w = pair_w[off + p];
                size_t gbase = (size_t)(off + p) * INTER + n0 + nb;
                #pragma unroll
                for (int nt = 0; nt < 2; nt++) {
                    float h1 = acc1[mt][nt][r];
                    float h3 = acc3[mt][nt][r];
                    float gv = h1 / (1.f + __expf(-h1)) * h3 * w;
                    G[gbase + nt * 16 + (lane & 15)] = f2bf(gv);
                }
            }
        }
    }
}

// ---------------- GEMM2: eo[p,d] = G[p,:] . w2[e][d,:]  (bf16, non-atomic) ----------------
// BM=128, BN=128, BK=64; grid mapping: IDENTITY (R2/R5-measured-best).
// R6's 8-phase 256^2 port was correct but +10us (1 block/CU + tail) — reverted.
__global__ __launch_bounds__(256, 3) void gemm2_kernel(
        const unsigned short* __restrict__ G,
        const unsigned short* __restrict__ w2b,
        unsigned short* __restrict__ eo,
        const int* __restrict__ meta) {
    int e  = blockIdx.z;
    int by = blockIdx.y;
    int bx = blockIdx.x;

    int cnt = meta[e];
    int m0 = by * 128;
    if (m0 >= cnt) return;
    int off = 0;
    for (int i = 0; i < e; i++) off += meta[i];
    int n0 = bx * 128;

    __shared__ __align__(16) unsigned short As[128 * 64];
    __shared__ __align__(16) unsigned short Bs[128 * 64];

    int tid = threadIdx.x;
    int wave = tid >> 6, lane = tid & 63;
    int kc = (lane & 7) ^ (lane >> 3);

    const unsigned short* sbase;
    unsigned short* ldst;
    unsigned soff[8];
    if (wave < 2) {
        sbase = G;
        ldst = As + wave * 4096;
        #pragma unroll
        for (int j = 0; j < 8; j++) {
            int row = (wave * 8 + j) * 8 + (lane >> 3);
            int p = m0 + row; p = p < cnt ? p : cnt - 1;
            soff[j] = (unsigned)(off + p) * INTER + (unsigned)(kc * 8);
        }
    } else {
        int g0 = (wave - 2) * 64;
        ldst = Bs + (wave - 2) * 4096;
        sbase = w2b + ((size_t)e * DIM + n0 + g0 + (lane >> 3)) * INTER + kc * 8;
    }

    int wm = wave >> 1, wn = wave & 1;
    int mb = wm * 64, nbw = wn * 64;
    v4f zero4 = {0.f, 0.f, 0.f, 0.f};
    v4f acc[4][4];
    #pragma unroll
    for (int i = 0; i < 4; i++)
        #pragma unroll
        for (int j = 0; j < 4; j++) acc[i][j] = zero4;

    for (int k0 = 0; k0 < INTER; k0 += 64) {
        if (wave < 2) {
            #pragma unroll
            for (int j = 0; j < 8; j++)
                gload_lds16(sbase + soff[j] + k0, ldst + j * 512);
        } else {
            #pragma unroll
            for (int j = 0; j < 8; j++)
                gload_lds16(sbase + (unsigned)(j * 8 * INTER) + k0, ldst + j * 512);
        }
        __syncthreads();
        #pragma unroll
        for (int s = 0; s < 2; s++) {
            int kk = s * 4 + (lane >> 4);
            v8s a[4], b[4];
            #pragma unroll
            for (int mt = 0; mt < 4; mt++) {
                int r = mb + mt * 16 + (lane & 15);
                a[mt] = *(const v8s*)&As[r * 64 + ((kk ^ (r & 7)) << 3)];
            }
            #pragma unroll
            for (int nt = 0; nt < 4; nt++) {
                int n = nbw + nt * 16 + (lane & 15);
                b[nt] = *(const v8s*)&Bs[n * 64 + ((kk ^ (n & 7)) << 3)];
            }
            #pragma unroll
            for (int mt = 0; mt < 4; mt++)
                #pragma unroll
                for (int nt = 0; nt < 4; nt++)
                    acc[mt][nt] = __builtin_amdgcn_mfma_f32_16x16x32_bf16(a[mt], b[nt], acc[mt][nt], 0, 0, 0);
        }
        __syncthreads();
    }

    #pragma unroll
    for (int mt = 0; mt < 4; mt++) {
        #pragma unroll
        for (int r = 0; r < 4; r++) {
            int row = mb + mt * 16 + ((lane >> 4) << 2) + r;
            int p = m0 + row;
            if (p < cnt) {
                unsigned short* obase = eo + (size_t)(off + p) * DIM + n0 + nbw;
                #pragma unroll
                for (int nt = 0; nt < 4; nt++)
                    obase[nt * 16 + (lane & 15)] = f2bf(acc[mt][nt][r]);
            }
        }
    }
}

// ---------------- combine: out[t,:] = eo[p1,:] + eo[p2,:] + eo[p3,:] ----------------
__global__ __launch_bounds__(256) void combine_kernel(const unsigned short* __restrict__ eo,
                                                      const int* __restrict__ slots,
                                                      float* __restrict__ out) {
    int t = blockIdx.x;
    int p0 = slots[t * 3 + 0], p1 = slots[t * 3 + 1], p2 = slots[t * 3 + 2];
    const ushort4* r0 = (const ushort4*)(eo + (size_t)p0 * DIM);
    const ushort4* r1 = (const ushort4*)(eo + (size_t)p1 * DIM);
    const ushort4* r2 = (const ushort4*)(eo + (size_t)p2 * DIM);
    float4* o = (float4*)(out + (size_t)t * DIM);
    for (int i = threadIdx.x; i < DIM / 4; i += 256) {
        ushort4 a = r0[i], b = r1[i], c = r2[i];
        float4 v;
        v.x = __uint_as_float((unsigned)a.x << 16) + __uint_as_float((unsigned)b.x << 16) + __uint_as_float((unsigned)c.x << 16);
        v.y = __uint_as_float((unsigned)a.y << 16) + __uint_as_float((unsigned)b.y << 16) + __uint_as_float((unsigned)c.y << 16);
        v.z = __uint_as_float((unsigned)a.z << 16) + __uint_as_float((unsigned)b.z << 16) + __uint_as_float((unsigned)c.z << 16);
        v.w = __uint_as_float((unsigned)a.w << 16) + __uint_as_float((unsigned)b.w << 16) + __uint_as_float((unsigned)c.w << 16);
        o[i] = v;
    }
}

// ---------------- launch ----------------
extern "C" void kernel_launch(void* const* d_in, const int* in_sizes, int n_in,
                              void* d_out, int out_size, void* d_ws, size_t ws_size,
                              hipStream_t stream) {
    const float* x   = (const float*)d_in[0];
    const float* gw  = (const float*)d_in[1];
    const float* w1  = (const float*)d_in[2];
    const float* w2  = (const float*)d_in[3];
    const float* w3  = (const float*)d_in[4];
    const float* ws1 = (const float*)d_in[5];
    const float* ws2 = (const float*)d_in[6];
    const float* ws3 = (const float*)d_in[7];
    float* out = (float*)d_out;

    char* p = (char*)d_ws;
    auto alloc = [&](size_t bytes) {
        void* r = (void*)p;
        p += (bytes + 255) & ~(size_t)255;
        return r;
    };
    unsigned short* xb  = (unsigned short*)alloc((size_t)T_TOK * DIM * 2);
    unsigned short* w1b = (unsigned short*)alloc((size_t)NE * INTER * DIM * 2);
    unsigned short* w3b = (unsigned short*)alloc((size_t)NE * INTER * DIM * 2);
    unsigned short* w2b = (unsigned short*)alloc((size_t)NE * DIM * INTER * 2);
    unsigned short* G   = (unsigned short*)alloc((size_t)NPAIR * INTER * 2);
    int*   ei    = (int*)alloc((size_t)T_TOK * 3 * 4);
    float* wt    = (float*)alloc((size_t)T_TOK * 3 * 4);
    int*   ptok  = (int*)alloc((size_t)NPAIR * 4);
    float* pw    = (float*)alloc((size_t)NPAIR * 4);
    int*   slots = (int*)alloc((size_t)NPAIR * 4);
    int*   meta  = (int*)alloc(32 * 4);
    // eo (12288 x 2048 bf16 = 50.3 MB) aliases w1b+w3b (75.5 MB): dead after gemm1
    unsigned short* eo = w1b;

    prep_kernel<<<2 * WCVT + T_TOK, 256, 0, stream>>>(w1, ws1, w1b, w3, ws3, w3b,
                                                      x, gw, wt, ei, xb, meta);
    count_kernel<<<T_TOK / 256, 256, 0, stream>>>(ei, meta);
    fill_kernel<<<T_TOK / 256, 256, 0, stream>>>(ei, wt, meta, ptok, pw, slots);
    gemm1_kernel<<<dim3(INTER / 64, 40, NE), 256, 0, stream>>>(xb, w1b, w3b, G, meta, ptok, pw,
                                                               w2, ws2, w2b);
    gemm2_kernel<<<dim3(DIM / 128, 32, NE), 256, 0, stream>>>(G, w2b, eo, meta);
    combine_kernel<<<T_TOK, 256, 0, stream>>>(eo, slots, out);
}